// Round 1
// baseline (255.567 us; speedup 1.0000x reference)
//
#include <hip/hip_runtime.h>
#include <math.h>

#define BS 8192
#define HALF 4096
#define DIM 1024
#define TAU_INV 20.0f
#define BIGP 1.0e10f

typedef __attribute__((ext_vector_type(8))) short bf16x8;
typedef __attribute__((ext_vector_type(4))) float f32x4;

__device__ inline unsigned short f2bf(float f) {
    union { float f; unsigned int u; } c; c.f = f;
    unsigned int u = c.u;
    u += 0x7FFFu + ((u >> 16) & 1u);
    return (unsigned short)(u >> 16);
}

// ---------------------------------------------------------------------------
// 1) Row-normalize concat(f1,f2), convert to bf16, store to ws.
//    One block per row, 256 threads, 4 floats/thread.
// ---------------------------------------------------------------------------
__global__ __launch_bounds__(256) void norm_kernel(const float* __restrict__ f1,
                                                   const float* __restrict__ f2,
                                                   unsigned short* __restrict__ nb) {
    const int row = blockIdx.x;
    const int t = threadIdx.x;
    const float* src = (row < HALF) ? (f1 + (size_t)row * DIM)
                                    : (f2 + (size_t)(row - HALF) * DIM);
    float4 v = reinterpret_cast<const float4*>(src)[t];
    float ss = v.x * v.x + v.y * v.y + v.z * v.z + v.w * v.w;
#pragma unroll
    for (int off = 32; off > 0; off >>= 1) ss += __shfl_down(ss, off, 64);
    __shared__ float red[4];
    if ((t & 63) == 0) red[t >> 6] = ss;
    __syncthreads();
    float tot = red[0] + red[1] + red[2] + red[3];
    float inv = 1.0f / fmaxf(sqrtf(tot), 1e-8f);
    ushort4 o;
    o.x = f2bf(v.x * inv);
    o.y = f2bf(v.y * inv);
    o.z = f2bf(v.z * inv);
    o.w = f2bf(v.w * inv);
    reinterpret_cast<ushort4*>(nb + (size_t)row * DIM)[t] = o;
}

// ---------------------------------------------------------------------------
// 2) S = N * N^T (bf16 MFMA), epilogue: logits = S/tau - eye*1e10 -> d_out+1
//    128x128 tile per 256-thread block (4 waves, 2x2), BK=64, padded LDS.
// ---------------------------------------------------------------------------
#define BM 128
#define BN 128
#define BK 64
#define LDK 72  // +8 ushort pad (16B) -> row stride 144B, breaks 32-way conflicts

__global__ __launch_bounds__(256) void gemm_kernel(const unsigned short* __restrict__ nb,
                                                   float* __restrict__ logits) {
    __shared__ unsigned short As[BM][LDK];
    __shared__ unsigned short Bs[BN][LDK];

    const int t = threadIdx.x;
    const int lane = t & 63;
    const int wid = t >> 6;
    const int wr = wid >> 1;  // wave row (0..1), 64 rows each
    const int wc = wid & 1;   // wave col (0..1), 64 cols each

    const int rowBase = blockIdx.y * BM;
    const int colBase = blockIdx.x * BN;

    f32x4 acc[4][4];
#pragma unroll
    for (int m = 0; m < 4; ++m)
#pragma unroll
        for (int n = 0; n < 4; ++n) {
            acc[m][n][0] = 0.f; acc[m][n][1] = 0.f;
            acc[m][n][2] = 0.f; acc[m][n][3] = 0.f;
        }

    for (int kt = 0; kt < DIM; kt += BK) {
        // stage A(128x64) and B(128x64) bf16 tiles: 4 x 16B chunks per thread each
#pragma unroll
        for (int c = 0; c < 4; ++c) {
            int idx = (c * 256 + t) * 8;  // element index within 128x64 tile
            int r = idx >> 6;
            int k = idx & 63;
            const unsigned short* gA = nb + (size_t)(rowBase + r) * DIM + kt + k;
            *reinterpret_cast<int4*>(&As[r][k]) = *reinterpret_cast<const int4*>(gA);
            const unsigned short* gB = nb + (size_t)(colBase + r) * DIM + kt + k;
            *reinterpret_cast<int4*>(&Bs[r][k]) = *reinterpret_cast<const int4*>(gB);
        }
        __syncthreads();

#pragma unroll
        for (int ks = 0; ks < BK; ks += 32) {
            bf16x8 a[4], b[4];
#pragma unroll
            for (int m = 0; m < 4; ++m)
                a[m] = *reinterpret_cast<const bf16x8*>(
                    &As[wr * 64 + m * 16 + (lane & 15)][ks + (lane >> 4) * 8]);
#pragma unroll
            for (int n = 0; n < 4; ++n)
                b[n] = *reinterpret_cast<const bf16x8*>(
                    &Bs[wc * 64 + n * 16 + (lane & 15)][ks + (lane >> 4) * 8]);
#pragma unroll
            for (int m = 0; m < 4; ++m)
#pragma unroll
                for (int n = 0; n < 4; ++n)
                    acc[m][n] = __builtin_amdgcn_mfma_f32_16x16x32_bf16(a[m], b[n], acc[m][n], 0, 0, 0);
        }
        __syncthreads();
    }

    // epilogue: logits = acc/tau - BIGP on diagonal
    // C/D mapping (m89-verified): col = lane&15, row = (lane>>4)*4 + reg
#pragma unroll
    for (int m = 0; m < 4; ++m) {
#pragma unroll
        for (int n = 0; n < 4; ++n) {
            int col = colBase + wc * 64 + n * 16 + (lane & 15);
#pragma unroll
            for (int r = 0; r < 4; ++r) {
                int row = rowBase + wr * 64 + m * 16 + (lane >> 4) * 4 + r;
                float v = acc[m][n][r] * TAU_INV;
                if (row == col) v -= BIGP;
                logits[(size_t)row * BS + col] = v;
            }
        }
    }
}

// ---------------------------------------------------------------------------
// 3) Per-row: M = max, S = sum exp(x-M), per_example = -(logit[y]-M-log S)
//    wl[row] = w*pe, wsum[row] = w.  One block per row, 32 elems/thread.
// ---------------------------------------------------------------------------
__global__ __launch_bounds__(256) void row_lse_kernel(const float* __restrict__ logits,
                                                      const int* __restrict__ mask,
                                                      float* __restrict__ wl,
                                                      float* __restrict__ wsum) {
    const int row = blockIdx.x;
    const int t = threadIdx.x;
    const float* lr = logits + (size_t)row * BS;

    float vals[32];
    float mx = -3.0e38f;
#pragma unroll
    for (int i = 0; i < 32; ++i) {
        vals[i] = lr[t + i * 256];
        mx = fmaxf(mx, vals[i]);
    }
#pragma unroll
    for (int off = 32; off > 0; off >>= 1) mx = fmaxf(mx, __shfl_down(mx, off, 64));
    __shared__ float redm[4], reds[4];
    if ((t & 63) == 0) redm[t >> 6] = mx;
    __syncthreads();
    float M = fmaxf(fmaxf(redm[0], redm[1]), fmaxf(redm[2], redm[3]));

    float s = 0.f;
#pragma unroll
    for (int i = 0; i < 32; ++i) s += __expf(vals[i] - M);
#pragma unroll
    for (int off = 32; off > 0; off >>= 1) s += __shfl_down(s, off, 64);
    if ((t & 63) == 0) reds[t >> 6] = s;
    __syncthreads();

    if (t == 0) {
        float S = reds[0] + reds[1] + reds[2] + reds[3];
        int yt = (row < HALF) ? row + HALF : row - HALF;
        float target = lr[yt];
        float pe = -(target - M - logf(S));
        float w = 1.0f - (float)mask[row & (HALF - 1)];
        wl[row] = w * pe;
        wsum[row] = w;
    }
}

// ---------------------------------------------------------------------------
// 4) loss = sum(wl)/sum(wsum) -> d_out[0]; also write y_true as f32.
// ---------------------------------------------------------------------------
__global__ __launch_bounds__(256) void finalize_kernel(const float* __restrict__ wl,
                                                       const float* __restrict__ wsum,
                                                       float* __restrict__ loss_out,
                                                       float* __restrict__ ytrue_out) {
    const int t = threadIdx.x;
    float a = 0.f, b = 0.f;
    for (int i = t; i < BS; i += 256) { a += wl[i]; b += wsum[i]; }
#pragma unroll
    for (int off = 32; off > 0; off >>= 1) {
        a += __shfl_down(a, off, 64);
        b += __shfl_down(b, off, 64);
    }
    __shared__ float ra[4], rb[4];
    if ((t & 63) == 0) { ra[t >> 6] = a; rb[t >> 6] = b; }
    __syncthreads();
    if (t == 0) {
        float A = ra[0] + ra[1] + ra[2] + ra[3];
        float B = rb[0] + rb[1] + rb[2] + rb[3];
        loss_out[0] = A / B;
    }
    for (int i = t; i < BS; i += 256)
        ytrue_out[i] = (float)((i < HALF) ? i + HALF : i - HALF);
}

// ---------------------------------------------------------------------------
extern "C" void kernel_launch(void* const* d_in, const int* in_sizes, int n_in,
                              void* d_out, int out_size, void* d_ws, size_t ws_size,
                              hipStream_t stream) {
    const float* f1 = (const float*)d_in[0];
    const float* f2 = (const float*)d_in[1];
    const int* mask = (const int*)d_in[2];
    float* out = (float*)d_out;

    unsigned short* nb = (unsigned short*)d_ws;                      // 16 MB bf16 normalized
    float* wl = (float*)((char*)d_ws + (size_t)BS * DIM * 2);        // 32 KB
    float* wsum = wl + BS;                                           // 32 KB
    float* logits = out + 1;

    norm_kernel<<<BS, 256, 0, stream>>>(f1, f2, nb);

    dim3 g(BS / BN, BS / BM);
    gemm_kernel<<<g, 256, 0, stream>>>(nb, logits);

    row_lse_kernel<<<BS, 256, 0, stream>>>(logits, mask, wl, wsum);

    finalize_kernel<<<1, 256, 0, stream>>>(wl, wsum, out, out + 1 + (size_t)BS * BS);
}